// Round 5
// baseline (65.240 us; speedup 1.0000x reference)
//
#include <hip/hip_runtime.h>
#include <hip/hip_bf16.h>

// Problem constants
constexpr int BB = 8;
constexpr int LLEN = 2048;
constexpr int HH = 256;
constexpr int EE = 512;          // H * EXP
constexpr int MM = BB * LLEN;    // 16384 rows

typedef short bf16x8 __attribute__((ext_vector_type(8)));
typedef float f32x4  __attribute__((ext_vector_type(4)));

static __device__ inline unsigned short f2bf(float f) {
    unsigned u = __builtin_bit_cast(unsigned, f);
    unsigned r = (u + 0x7FFFu + ((u >> 16) & 1u)) >> 16;
    return (unsigned short)r;
}
static __device__ inline float bf2f(unsigned short h) {
    return __builtin_bit_cast(float, (unsigned)h << 16);
}

#define GL2LDS(gp, lp) __builtin_amdgcn_global_load_lds( \
    (const __attribute__((address_space(1))) void*)(gp), \
    (__attribute__((address_space(3))) void*)(lp), 16, 0, 0)

// ---------------------------------------------------------------------------
// cast f32 -> bf16, 4 elems/thread; XCD-swizzled so rows chain into K1's L2.
// ---------------------------------------------------------------------------
__global__ __launch_bounds__(256) void cast_bf16_kernel(
    const float* __restrict__ in, unsigned short* __restrict__ out)
{
    int b = blockIdx.x;
    int cpx = gridDim.x >> 3;
    int lin = (b & 7) * cpx + (b >> 3);
    int i = (lin * 256 + threadIdx.x) * 4;
    float4 v = *reinterpret_cast<const float4*>(in + i);
    ushort4 o = {f2bf(v.x), f2bf(v.y), f2bf(v.z), f2bf(v.w)};
    *reinterpret_cast<ushort4*>(out + i) = o;
}

// ---------------------------------------------------------------------------
// Wt[n][k] = (bf16) W[k][n]   (output-contiguous)
// ---------------------------------------------------------------------------
__global__ __launch_bounds__(256) void transpose_cast_kernel(
    const float* __restrict__ W, unsigned short* __restrict__ Wt, int K, int N)
{
    int i = blockIdx.x * 256 + threadIdx.x;
    if (i < K * N) {
        int n = i / K, k = i - n * K;
        Wt[i] = f2bf(W[(size_t)k * N + n]);
    }
}

// ---------------------------------------------------------------------------
// bf16 MFMA GEMM, ring-buffered pipeline: BK=32, NBUF=4 LDS buffers,
// prefetch depth 3, counted vmcnt (loads issued 3 iters before their wait).
// C = A[M,K]bf16 @ Bt[N,K]bf16^T + bias, split store.
// Tile BM x BN, 256 thr = 4 waves (2 x WCOLS); wave tile (MFR*16)x(NFR*16).
// LDS XOR swizzle: 16B slot s of row r stored at s^((r>>1)&3) (pre-swizzled
// global source for global_load_lds + same XOR on ds_read; 64B row stride
// -> bank = f(r&1, slot), (r>>1) XOR spreads 16 lanes over 8 bank-groups).
// XCD-chunk blockIdx swizzle (grid % 8 == 0).
// ---------------------------------------------------------------------------
template<int BM, int BN, int K, int MFR, int NFR, int GX, bool BF16OUT, bool SILU1>
__global__ __launch_bounds__(256) void gemm3(
    const unsigned short* __restrict__ A, const unsigned short* __restrict__ Bt,
    const float* __restrict__ bias, void* __restrict__ C0v, void* __restrict__ C1v,
    int split, int ldc0, int ldc1)
{
    constexpr int BK = 32;
    constexpr int NT = K / BK;          // K1: 8, K3: 16
    constexpr int NBUF = 4;
    constexpr int AL = BM * BK / (256 * 8);   // per-thread A gload_lds
    constexpr int BL = BN * BK / (256 * 8);
    constexpr int NL = AL + BL;               // loads per stage (vmcnt quantum)
    constexpr int WCOLS = BN / (16 * NFR);

    __shared__ unsigned short Al[NBUF][BM * BK];
    __shared__ unsigned short Bl[NBUF][BN * BK];

    const int tid = threadIdx.x;
    const int lane = tid & 63;
    const int wave = tid >> 6;
    const int wrow = wave / WCOLS, wcol = wave % WCOLS;
    const int l15 = lane & 15;
    const int lk  = lane >> 4;

    // XCD-chunk swizzle (bijective since grid % 8 == 0)
    const int cpx = gridDim.x >> 3;
    int lin = blockIdx.x;
    lin = (lin & 7) * cpx + (lin >> 3);
    const int row0 = (lin / GX) * BM;
    const int col0 = (lin % GX) * BN;

    f32x4 acc[MFR][NFR] = {};

    auto stage = [&](int bi, int kt) {
        const unsigned short* Ab = A + (size_t)row0 * K + kt;
        #pragma unroll
        for (int i = 0; i < AL; ++i) {
            int sid = i * 256 + tid;
            int r = sid >> 2, sl = sid & 3;
            GL2LDS(Ab + (size_t)r * K + ((sl ^ ((r >> 1) & 3)) << 3), &Al[bi][sid * 8]);
        }
        const unsigned short* Bb = Bt + (size_t)col0 * K + kt;
        #pragma unroll
        for (int i = 0; i < BL; ++i) {
            int sid = i * 256 + tid;
            int r = sid >> 2, sl = sid & 3;
            GL2LDS(Bb + (size_t)r * K + ((sl ^ ((r >> 1) & 3)) << 3), &Bl[bi][sid * 8]);
        }
    };

    // prologue: 3 stages in flight
    stage(0, 0);
    stage(1, BK);
    stage(2, 2 * BK);

    #pragma unroll
    for (int t = 0; t < NT; ++t) {
        const int bi = t & (NBUF - 1);
        if (t + 3 < NT)
            stage((t + 3) & (NBUF - 1), (t + 3) * BK);   // stays in flight 3 iters

        // wait for tile t only: fut future stages remain outstanding
        const int fut = (NT - 1 - t) < 3 ? (NT - 1 - t) : 3;
        switch (fut) {
            case 3: asm volatile("s_waitcnt vmcnt(%0)" :: "n"(3 * NL) : "memory"); break;
            case 2: asm volatile("s_waitcnt vmcnt(%0)" :: "n"(2 * NL) : "memory"); break;
            case 1: asm volatile("s_waitcnt vmcnt(%0)" :: "n"(NL) : "memory"); break;
            default: asm volatile("s_waitcnt vmcnt(0)" ::: "memory"); break;
        }
        __builtin_amdgcn_sched_barrier(0);
        __builtin_amdgcn_s_barrier();      // all waves' tile-t loads landed
        __builtin_amdgcn_sched_barrier(0);

        bf16x8 af[MFR], bfr[NFR];
        #pragma unroll
        for (int m = 0; m < MFR; ++m) {
            const int r = wrow * (MFR * 16) + m * 16 + l15;
            const int sl = lk ^ ((r >> 1) & 3);
            af[m] = *reinterpret_cast<const bf16x8*>(&Al[bi][r * 32 + sl * 8]);
        }
        #pragma unroll
        for (int n = 0; n < NFR; ++n) {
            const int r = wcol * (NFR * 16) + n * 16 + l15;
            const int sl = lk ^ ((r >> 1) & 3);
            bfr[n] = *reinterpret_cast<const bf16x8*>(&Bl[bi][r * 32 + sl * 8]);
        }
        #pragma unroll
        for (int m = 0; m < MFR; ++m)
            #pragma unroll
            for (int n = 0; n < NFR; ++n)
                acc[m][n] = __builtin_amdgcn_mfma_f32_16x16x32_bf16(
                    af[m], bfr[n], acc[m][n], 0, 0, 0);

        __builtin_amdgcn_s_barrier();      // reads of buf[bi] done (next stage reuses it)
    }

    // epilogue: C/D layout col = lane&15, row = (lane>>4)*4 + i
    #pragma unroll
    for (int m = 0; m < MFR; ++m) {
        #pragma unroll
        for (int n = 0; n < NFR; ++n) {
            int col = col0 + wcol * (NFR * 16) + n * 16 + l15;
            float bv = bias[col];
            #pragma unroll
            for (int i = 0; i < 4; ++i) {
                int row = row0 + wrow * (MFR * 16) + m * 16 + lk * 4 + i;
                float v = acc[m][n][i] + bv;
                if (col < split) {
                    if (BF16OUT)
                        ((unsigned short*)C0v)[(size_t)row * ldc0 + col] = f2bf(v);
                    else
                        ((float*)C0v)[(size_t)row * ldc0 + col] = v;
                } else {
                    float w = SILU1 ? (v / (1.f + __expf(-v))) : v;
                    if (BF16OUT)
                        ((unsigned short*)C1v)[(size_t)row * ldc1 + (col - split)] = f2bf(w);
                    else
                        ((float*)C1v)[(size_t)row * ldc1 + (col - split)] = w;
                }
            }
        }
    }
}

// ---------------------------------------------------------------------------
// Fused middle: depthwise conv(k=3,pad=1 along L) + SiLU + Dp* + LayerNorm(E)
//               + *silu(z)  -> gbuf (bf16, feeds K3).
// Wave-per-row: 64 lanes x 8 contiguous e = 512 = E. 4 rows per block.
// SSM scan output is constant over E (h0=0, input term broadcasts over E),
// so LayerNorm cancels it exactly -> skipped. W_x/b_x/A_log are dead inputs.
// ---------------------------------------------------------------------------
__global__ __launch_bounds__(256) void mid_kernel(
    const unsigned short* __restrict__ x, const unsigned short* __restrict__ zs,
    unsigned short* __restrict__ g,
    const float* __restrict__ conv_w, const float* __restrict__ conv_b,
    const float* __restrict__ Dp, const float* __restrict__ ln_g,
    const float* __restrict__ ln_b)
{
    const int lane = threadIdx.x & 63;
    const int wid  = threadIdx.x >> 6;
    int b = blockIdx.x;
    int cpx = gridDim.x >> 3;
    int lin = (b & 7) * cpx + (b >> 3);       // XCD chunk, aligned with GEMMs
    const int row  = lin * 4 + wid;           // b*L + l
    const int l    = row & (LLEN - 1);
    const int e0   = lane * 8;
    const size_t base = (size_t)row * EE + e0;

    bf16x8 xc = *reinterpret_cast<const bf16x8*>(x + base);
    bf16x8 xm = {}, xp = {};
    if (l > 0)        xm = *reinterpret_cast<const bf16x8*>(x + base - EE);
    if (l < LLEN - 1) xp = *reinterpret_cast<const bf16x8*>(x + base + EE);

    float o[8];
    float s1 = 0.f, s2 = 0.f;
    #pragma unroll
    for (int j = 0; j < 8; ++j) {
        int e = e0 + j;
        float v = conv_b[e]
                + bf2f((unsigned short)xm[j]) * conv_w[e * 3 + 0]
                + bf2f((unsigned short)xc[j]) * conv_w[e * 3 + 1]
                + bf2f((unsigned short)xp[j]) * conv_w[e * 3 + 2];
        float sx = v / (1.f + __expf(-v));   // silu
        float oe = Dp[e] * sx;
        o[j] = oe;
        s1 += oe;
        s2 += oe * oe;
    }

    // full-wave butterfly reduce (all lanes get the sums)
    #pragma unroll
    for (int off = 1; off < 64; off <<= 1) {
        s1 += __shfl_xor(s1, off);
        s2 += __shfl_xor(s2, off);
    }

    const float mu  = s1 * (1.f / EE);
    const float var = s2 * (1.f / EE) - mu * mu;
    const float inv = rsqrtf(var + 1e-5f);

    bf16x8 zv = *reinterpret_cast<const bf16x8*>(zs + base);
    bf16x8 ov;
    #pragma unroll
    for (int j = 0; j < 8; ++j) {
        int e = e0 + j;
        float gy = ((o[j] - mu) * inv * ln_g[e] + ln_b[e]) * bf2f((unsigned short)zv[j]);
        ov[j] = (short)f2bf(gy);
    }
    *reinterpret_cast<bf16x8*>(g + base) = ov;
}

// ---------------------------------------------------------------------------
extern "C" void kernel_launch(void* const* d_in, const int* in_sizes, int n_in,
                              void* d_out, int out_size, void* d_ws, size_t ws_size,
                              hipStream_t stream)
{
    const float* u      = (const float*)d_in[0];
    const float* W_in   = (const float*)d_in[1];
    const float* b_in   = (const float*)d_in[2];
    const float* conv_w = (const float*)d_in[3];
    const float* conv_b = (const float*)d_in[4];
    // d_in[5]=W_x, d_in[6]=b_x, d_in[7]=A_log: dead (scan cancels under LN)
    const float* Dp     = (const float*)d_in[8];
    const float* W_out  = (const float*)d_in[9];
    const float* b_out  = (const float*)d_in[10];
    const float* ln_g   = (const float*)d_in[11];
    const float* ln_b   = (const float*)d_in[12];
    float* out = (float*)d_out;

    // workspace carve-up (all bf16 intermediates)
    char* ws = (char*)d_ws;
    unsigned short* ubf   = (unsigned short*)ws; ws += (size_t)MM * HH * 2;    // 8.4MB
    unsigned short* wtin  = (unsigned short*)ws; ws += (size_t)1024 * HH * 2;  // 0.5MB
    unsigned short* wtout = (unsigned short*)ws; ws += (size_t)HH * EE * 2;    // 0.25MB
    unsigned short* xbuf  = (unsigned short*)ws; ws += (size_t)MM * EE * 2;    // 16.8MB
    unsigned short* zsbuf = (unsigned short*)ws; ws += (size_t)MM * EE * 2;    // 16.8MB  silu(z)
    unsigned short* gbuf  = (unsigned short*)ws;                               // 16.8MB

    dim3 blk(256);

    // prep: casts + weight transposes
    cast_bf16_kernel<<<dim3(MM * HH / 1024), blk, 0, stream>>>(u, ubf);
    transpose_cast_kernel<<<dim3((1024 * HH + 255) / 256), blk, 0, stream>>>(W_in, wtin, HH, 1024);
    transpose_cast_kernel<<<dim3((HH * EE + 255) / 256), blk, 0, stream>>>(W_out, wtout, EE, HH);

    // K1: xz = u @ W_in + b_in ; cols [0,512)->x bf16, [512,1024)->silu(z) bf16
    // tile 64x128, grid 256x8 = 2048 blocks, 48KB LDS -> 3 blocks/CU
    gemm3<64, 128, HH, 2, 4, 8, true, true><<<dim3(2048), blk, 0, stream>>>(
        ubf, wtin, b_in, xbuf, zsbuf, EE, EE, EE);

    // K2: conv+silu+Dp*+LN+*silu(z) -> gbuf bf16
    mid_kernel<<<dim3(MM / 4), blk, 0, stream>>>(
        xbuf, zsbuf, gbuf, conv_w, conv_b, Dp, ln_g, ln_b);

    // K3: out = gbuf @ W_out + b_out (f32 out)
    // tile 64x64, grid 256x4 = 1024 blocks, 32KB LDS -> 5 blocks/CU
    gemm3<64, 64, EE, 2, 2, 4, false, false><<<dim3(1024), blk, 0, stream>>>(
        gbuf, wtout, b_out, out, out, 1 << 30, HH, HH);
}